// Round 12
// baseline (1374.439 us; speedup 1.0000x reference)
//
#include <hip/hip_runtime.h>
#include <cstdint>
#include <cstddef>

#define DEV static __device__ __forceinline__

typedef float  f32x4 __attribute__((ext_vector_type(4)));
typedef float  f32x2 __attribute__((ext_vector_type(2)));
typedef short  s16x8 __attribute__((ext_vector_type(8)));
typedef unsigned short u16;
typedef unsigned int   u32;
typedef unsigned int   u32x4 __attribute__((ext_vector_type(4)));
typedef unsigned short u16x2 __attribute__((ext_vector_type(2)));
typedef unsigned short u16x4 __attribute__((ext_vector_type(4)));
typedef __bf16 bf16x8 __attribute__((ext_vector_type(8)));

#define LOG2E 1.4426950408889634f
#define QSCALE_CONST 0.18033688011112042f   /* 0.125 * log2(e) */
#define BSCALE 256.0f                       /* bias fp8 pre-scale */
#define BINV   0.00390625f                  /* 1/256 */

DEV u16 f2bf(float f){ return __builtin_bit_cast(u16, (__bf16)f); }
DEV float bf2f(u16 v){ union { unsigned u; float f; } x; x.u = ((unsigned)v) << 16; return x.f; }

DEV float fexp2(float x){
#if __has_builtin(__builtin_amdgcn_exp2f)
  return __builtin_amdgcn_exp2f(x);
#else
  return exp2f(x);
#endif
}

DEV f32x4 mfma16(s16x8 a, s16x8 b, f32x4 c){
  return __builtin_amdgcn_mfma_f32_16x16x32_bf16(
      __builtin_bit_cast(bf16x8, a), __builtin_bit_cast(bf16x8, b), c, 0, 0, 0);
}

// async global->LDS, 16B per lane
DEV void gld16(const void* g, void* l){
  __builtin_amdgcn_global_load_lds(
      (const __attribute__((address_space(1))) void*)(uintptr_t)g,
      (__attribute__((address_space(3))) void*)(unsigned)(uintptr_t)l,
      16, 0, 0);
}

// ---- fp8 e4m3 (OCP) pack/unpack; HI is compile-time for the builtin ----
#if __has_builtin(__builtin_amdgcn_cvt_pk_fp8_f32) && __has_builtin(__builtin_amdgcn_cvt_pk_f32_fp8)
DEV u32 pk4_fp8(f32x4 v){
  int r = __builtin_amdgcn_cvt_pk_fp8_f32(v[0], v[1], 0, false);
  r     = __builtin_amdgcn_cvt_pk_fp8_f32(v[2], v[3], r, true);
  return (u32)r;
}
template<bool HI>
DEV f32x2 upk_fp8(u32 w){
  return __builtin_amdgcn_cvt_pk_f32_fp8((int)w, HI);
}
#else
DEV unsigned enc1(float x){
  union{float f; unsigned u;} c; c.f = x;
  unsigned s = (c.u >> 24) & 0x80;
  int e = (int)((c.u >> 23) & 0xff) - 127;
  unsigned m = c.u & 0x7fffff;
  if (e >= -6){
    unsigned mant = m >> 20, rem = m & 0xfffff;
    if (rem > 0x80000 || (rem == 0x80000 && (mant & 1))) mant++;
    unsigned eb = (unsigned)(e + 7);
    if (mant == 8){ mant = 0; eb++; }
    if (eb >= 16){ eb = 15; mant = 6; }
    return s | (eb << 3) | mant;
  }
  if (e < -10) return s;
  int sh = -6 - e;
  unsigned full = (1u << 23) | m;
  unsigned mant = full >> (20 + sh);
  unsigned rem  = full & ((1u << (20 + sh)) - 1);
  unsigned half = 1u << (19 + sh);
  if (rem > half || (rem == half && (mant & 1))) mant++;
  if (mant == 8) return s | (1u << 3);
  return s | mant;
}
DEV u32 pk4_fp8(f32x4 v){
  return enc1(v[0]) | (enc1(v[1]) << 8) | (enc1(v[2]) << 16) | (enc1(v[3]) << 24);
}
DEV float dec1(unsigned b){
  int s = (b >> 7) & 1, e = (b >> 3) & 15; float m = (float)(b & 7) * 0.125f;
  float v = e ? ldexpf(1.0f + m, e - 7) : ldexpf(m, -6);
  return s ? -v : v;
}
template<bool HI>
DEV f32x2 upk_fp8(u32 w){
  unsigned lo = HI ? ((w >> 16) & 0xff) : (w & 0xff);
  unsigned h2 = HI ? ((w >> 24) & 0xff) : ((w >> 8) & 0xff);
  f32x2 r; r[0] = dec1(lo); r[1] = dec1(h2); return r;
}
#endif

// ---------------- transpose + fp32->bf16 convert: src[K][N] -> dst[N][K] ----------------
__global__ void __launch_bounds__(256)
transpose_cvt(const float* __restrict__ src, u16* __restrict__ dst, int K, int N,
              size_t dzstride){
  int z = blockIdx.z;
  src += (size_t)z * K * N;
  dst += (size_t)z * dzstride;
  __shared__ float t[32][33];
  int n0 = blockIdx.x * 32, k0 = blockIdx.y * 32;
#pragma unroll
  for (int i = 0; i < 4; ++i)
    t[threadIdx.y + 8*i][threadIdx.x] = src[(size_t)(k0 + threadIdx.y + 8*i) * N + n0 + threadIdx.x];
  __syncthreads();
#pragma unroll
  for (int i = 0; i < 4; ++i)
    dst[(size_t)(n0 + threadIdx.y + 8*i) * K + k0 + threadIdx.x] = f2bf(t[threadIdx.x][threadIdx.y + 8*i]);
}

// ---------------- batched 768x768 transpose (20 weights in one dispatch) ----------------
struct TPtrs { const float* src[20]; u16* dst[20]; };
__global__ void __launch_bounds__(256)
transpose_cvt_batch(TPtrs tp){
  const float* src = tp.src[blockIdx.z];
  u16* dst = tp.dst[blockIdx.z];
  __shared__ float t[32][33];
  int n0 = blockIdx.x * 32, k0 = blockIdx.y * 32;
#pragma unroll
  for (int i = 0; i < 4; ++i)
    t[threadIdx.y + 8*i][threadIdx.x] = src[(size_t)(k0 + threadIdx.y + 8*i) * 768 + n0 + threadIdx.x];
  __syncthreads();
#pragma unroll
  for (int i = 0; i < 4; ++i)
    dst[(size_t)(n0 + threadIdx.y + 8*i) * 768 + k0 + threadIdx.x] = f2bf(t[threadIdx.x][threadIdx.y + 8*i]);
}

// ---------------- bias -> tiled fp8 (log2e*256-scaled) ----------------
__global__ void __launch_bounds__(256)
cvt_biasT(const float* __restrict__ in, unsigned char* __restrict__ out){
  const int kvt = blockIdx.x, qt = blockIdx.y, h = blockIdx.z, tid = threadIdx.x;
  const int q  = qt * 64 + ((tid >> 6) << 4) + (tid & 15);
  const int c0 = kvt * 64 + ((tid >> 4) & 3) * 4;
  const float* src = in + ((size_t)h * 2048 + q) * 2048;
  u32x4 wv;
#pragma unroll
  for (int mi = 0; mi < 4; ++mi){
    f32x4 v = *(const f32x4*)(src + c0 + mi * 16);
#pragma unroll
    for (int r = 0; r < 4; ++r) v[r] = fminf(fmaxf(v[r] * (LOG2E * BSCALE), -448.f), 448.f);
    wv[mi] = pk4_fp8(v);
  }
  *(u32x4*)(out + ((size_t)(h * 32 + qt) * 32 + kvt) * 4096 + tid * 16) = wv;
}

// ---------------- pre-pass LN: stats computed ONCE per row ----------------
__global__ void __launch_bounds__(256)
ln_pre(const float* __restrict__ x, const float* __restrict__ ctx,
       const float* __restrict__ w1, const float* __restrict__ b1,
       const float* __restrict__ w2, const float* __restrict__ b2,
       u16* __restrict__ xn, u16* __restrict__ xbuf, u16* __restrict__ cn){
  const int wv = threadIdx.x >> 6, lane = threadIdx.x & 63;
  const int row = blockIdx.x * 4 + wv;
  const float* xr = (blockIdx.y == 0 ? x : ctx) + (size_t)row * 768;
  f32x4 t[3]; float s = 0.f, s2 = 0.f;
#pragma unroll
  for (int c = 0; c < 3; ++c){
    t[c] = *(const f32x4*)(xr + c * 256 + lane * 4);
#pragma unroll
    for (int j = 0; j < 4; ++j){ s += t[c][j]; s2 += t[c][j] * t[c][j]; }
  }
#pragma unroll
  for (int off = 1; off < 64; off <<= 1){ s += __shfl_xor(s, off); s2 += __shfl_xor(s2, off); }
  float m = s * (1.f/768.f);
  float rstd = rsqrtf(s2 * (1.f/768.f) - m * m + 1e-5f);
  if (blockIdx.y == 0){
#pragma unroll
    for (int c = 0; c < 3; ++c){
      const int col = c * 256 + lane * 4;
      f32x4 wv4 = *(const f32x4*)(w1 + col);
      f32x4 bv4 = *(const f32x4*)(b1 + col);
      u16x4 o, xb;
#pragma unroll
      for (int j = 0; j < 4; ++j){
        o[j]  = f2bf((t[c][j] - m) * rstd * wv4[j] + bv4[j]);
        xb[j] = f2bf(t[c][j]);
      }
      *(u16x4*)(xn   + (size_t)row * 768 + col) = o;
      *(u16x4*)(xbuf + (size_t)row * 768 + col) = xb;
    }
  } else {
#pragma unroll
    for (int i = 0; i < 4; ++i){
      u16* dst = cn + (size_t)i * 4096 * 768 + (size_t)row * 768;
#pragma unroll
      for (int c = 0; c < 3; ++c){
        const int col = c * 256 + lane * 4;
        f32x4 wv4 = *(const f32x4*)(w2 + i * 768 + col);
        f32x4 bv4 = *(const f32x4*)(b2 + i * 768 + col);
        u16x4 o;
#pragma unroll
        for (int j = 0; j < 4; ++j) o[j] = f2bf((t[c][j] - m) * rstd * wv4[j] + bv4[j]);
        *(u16x4*)(dst + col) = o;
      }
    }
  }
}

// ---------------- fused splitK(NZ)-reduce + bias + bf16 residual + LN, 2 rows/wave -----
template<typename OUT, int NZ>
__global__ void __launch_bounds__(256)
red_ln(const u16* __restrict__ pb, const float* __restrict__ biasrow,
       u16* __restrict__ xbuf, OUT* __restrict__ out,
       const float* __restrict__ lw, const float* __restrict__ lb){
  const int wv = threadIdx.x >> 6, lane = threadIdx.x & 63;
  const int row0 = blockIdx.x * 8 + wv * 2;
  const size_t S = 4096ll * 768;
  f32x4 t[2][3]; float s[2] = {0.f, 0.f}, s2[2] = {0.f, 0.f};
#pragma unroll
  for (int rr = 0; rr < 2; ++rr){
    const int row = row0 + rr;
    const u16* p0 = pb + (size_t)row * 768;
    u16* xr = xbuf + (size_t)row * 768;
#pragma unroll
    for (int c = 0; c < 3; ++c){
      const int col = c * 256 + lane * 4;
      f32x4 v = *(const f32x4*)(biasrow + col);
      u16x4 xv = *(const u16x4*)(xr + col);
#pragma unroll
      for (int j = 0; j < 4; ++j) v[j] += bf2f(xv[j]);
#pragma unroll
      for (int z = 0; z < NZ; ++z){
        u16x4 pv = *(const u16x4*)(p0 + z * S + col);
#pragma unroll
        for (int j = 0; j < 4; ++j) v[j] += bf2f(pv[j]);
      }
      u16x4 xo;
#pragma unroll
      for (int j = 0; j < 4; ++j) xo[j] = f2bf(v[j]);
      *(u16x4*)(xr + col) = xo;
      t[rr][c] = v;
#pragma unroll
      for (int j = 0; j < 4; ++j){ s[rr] += v[j]; s2[rr] += v[j] * v[j]; }
    }
  }
#pragma unroll
  for (int off = 1; off < 64; off <<= 1){
#pragma unroll
    for (int rr = 0; rr < 2; ++rr){
      s[rr]  += __shfl_xor(s[rr], off);
      s2[rr] += __shfl_xor(s2[rr], off);
    }
  }
#pragma unroll
  for (int rr = 0; rr < 2; ++rr){
    const int row = row0 + rr;
    float m = s[rr] * (1.f/768.f);
    float rstd = rsqrtf(s2[rr] * (1.f/768.f) - m * m + 1e-5f);
#pragma unroll
    for (int c = 0; c < 3; ++c){
      const int col = c * 256 + lane * 4;
      f32x4 wv4 = *(const f32x4*)(lw + col);
      f32x4 bv4 = *(const f32x4*)(lb + col);
      if constexpr (sizeof(OUT) == 2){
        u16x4 o;
#pragma unroll
        for (int j = 0; j < 4; ++j) o[j] = f2bf((t[rr][c][j] - m) * rstd * wv4[j] + bv4[j]);
        *(u16x4*)((u16*)out + (size_t)row * 768 + col) = o;
      } else {
        f32x4 o;
#pragma unroll
        for (int j = 0; j < 4; ++j) o[j] = (t[rr][c][j] - m) * rstd * wv4[j] + bv4[j];
        *(f32x4*)((float*)out + (size_t)row * 768 + col) = o;
      }
    }
  }
}

// ---------------- bf16 GEMM, 128x128, double-buffered, XCD-swizzled ----------------
template<int EPI>
__global__ void __launch_bounds__(256)
gemm_bf16(const u16* __restrict__ A, int lda, const u16* __restrict__ Bt, int ldb,
          int nk, u16* __restrict__ Cb, int ldc,
          const float* __restrict__ bias,
          const u16* __restrict__ A2, const u16* __restrict__ Bt2){
  __shared__ u16 As[2][128 * 32];
  __shared__ u16 Bs[2][128 * 32];
  float colscale = 1.0f;
  if constexpr (EPI == 4){
    const int z = blockIdx.z;
    if (z == 0){ colscale = QSCALE_CONST; }
    else { A = A2; Bt = Bt2 + (size_t)(z - 1) * 768 * 768; }
    Cb += z * 768;
  }
  if constexpr (EPI == 5){
    const int z = blockIdx.z;
    A  += (size_t)z * nk * 32;
    Bt += (size_t)z * nk * 32;
    Cb += (size_t)z * 4096 * 768;
  }
  // bijective XCD-chunked swizzle (m204) on the 2D slice
  const int gx = gridDim.x, nwg = gx * gridDim.y;
  int lin = blockIdx.y * gx + blockIdx.x;
  {
    const int qq = nwg >> 3, rr = nwg & 7;
    const int xc = lin & 7, oo = lin >> 3;
    lin = (xc < rr ? xc * (qq + 1) : rr * (qq + 1) + (xc - rr) * qq) + oo;
  }
  const int m0 = (lin % gx) * 128, n0 = (lin / gx) * 128;

  const int tid = threadIdx.x, w = tid >> 6, lane = tid & 63;
  const int l16 = lane & 15, g = lane >> 4;
  const int wm = (w >> 1) * 64, wn = (w & 1) * 64;
  f32x4 acc[4][4] = {};

  const u16* a0 = A  + (size_t)(m0 + (tid >> 2)) * lda + (tid & 3) * 8;
  const u16* a1 = A  + (size_t)(m0 + (tid >> 2) + 64) * lda + (tid & 3) * 8;
  const u16* b0 = Bt + (size_t)(n0 + (tid >> 2)) * ldb + (tid & 3) * 8;
  const u16* b1 = Bt + (size_t)(n0 + (tid >> 2) + 64) * ldb + (tid & 3) * 8;

  {
    char* ab = (char*)As[0]; char* bb = (char*)Bs[0];
    gld16(a0, ab + w * 1024); gld16(a1, ab + 4096 + w * 1024);
    gld16(b0, bb + w * 1024); gld16(b1, bb + 4096 + w * 1024);
  }
  __syncthreads();

  int cb = 0;
  for (int kt = 0; kt < nk; ++kt){
    if (kt + 1 < nk){
      const int k1 = (kt + 1) * 32;
      char* ab = (char*)As[cb ^ 1]; char* bb = (char*)Bs[cb ^ 1];
      gld16(a0 + k1, ab + w * 1024); gld16(a1 + k1, ab + 4096 + w * 1024);
      gld16(b0 + k1, bb + w * 1024); gld16(b1 + k1, bb + 4096 + w * 1024);
    }
    const u16* Ab = As[cb]; const u16* Bb = Bs[cb];
    s16x8 af[4], bfv[4];
#pragma unroll
    for (int mi = 0; mi < 4; ++mi)
      af[mi] = *(const s16x8*)(Ab + (wm + mi*16 + l16) * 32 + 8 * g);
#pragma unroll
    for (int ni = 0; ni < 4; ++ni)
      bfv[ni] = *(const s16x8*)(Bb + (wn + ni*16 + l16) * 32 + 8 * g);
#pragma unroll
    for (int mi = 0; mi < 4; ++mi)
#pragma unroll
      for (int ni = 0; ni < 4; ++ni)
        acc[mi][ni] = mfma16(af[mi], bfv[ni], acc[mi][ni]);
    __syncthreads();
    cb ^= 1;
  }

  // epilogue: C/D layout col = lane&15, row = 4*(lane>>4)+r
#pragma unroll
  for (int mi = 0; mi < 4; ++mi){
    const int rg = m0 + wm + mi*16 + 4*g;
#pragma unroll
    for (int ni = 0; ni < 4; ++ni){
      const int col = n0 + wn + ni*16 + l16;
      f32x4 v = acc[mi][ni];
#pragma unroll
      for (int r = 0; r < 4; ++r){
        const int row = rg + r;
        if constexpr (EPI == 2){
          float t = v[r] + bias[col];
          float ge = 0.5f * t * (1.0f + erff(t * 0.7071067811865476f));
          Cb[(size_t)row * ldc + col] = f2bf(ge);
        } else if constexpr (EPI == 3){
          float sc = (col < 768) ? QSCALE_CONST : 1.0f;
          Cb[(size_t)row * ldc + col] = f2bf(v[r] * sc);
        } else if constexpr (EPI == 4){
          Cb[(size_t)row * ldc + col] = f2bf(v[r] * colscale);
        } else {
          Cb[(size_t)row * 768 + col] = f2bf(v[r]);
        }
      }
    }
  }
}

// ---------------- fused flash attention v6: 2 waves x 32 q-rows (LDS-pressure halved) ---
// q pre-scaled by 0.125*log2e; biasT fp8 (log2e*256). QBLK=64 (2 waves x 32q), KV step 64.
// grid (32, 12, 2), 128 threads. LDS 40KB -> 4 blocks/CU = 8 waves/CU.
// Per wave per tile: QK^T 8 ds_read_b128 -> 16 MFMA (kf reused across 2 q-frags);
// PV 12 reads -> 16 MFMA. LDS ops per MFMA ~0.63 vs 1.13 in the 4-wave version.
__global__ void __launch_bounds__(128)
attn_kernel(const u16* __restrict__ qkv, const unsigned char* __restrict__ biasT,
            u16* __restrict__ out){
  __shared__ __align__(16) u16 Ks[2][4096];   // [buf][kv64][dh chunks, ^(row&7) swizzle]
  __shared__ __align__(16) u16 Vt[2][4096];   // [buf][dh64][kv chunks, ^(dh&7) swizzle]
  __shared__ __align__(16) u16 Pl[2][2048];   // per-wave P [q32][kv chunks swizzled]

  const int tid = threadIdx.x, w = tid >> 6, lane = tid & 63;
  const int l16 = lane & 15, g = lane >> 4;
  const int qt = blockIdx.x, h = blockIdx.y, b = blockIdx.z;
  const int rowbase = b * 2048, q0 = qt * 64;

  // K staging: 4 gld16 per thread (512 chunks / 128 threads), pre-swizzled source
  const u16* kp[4];
#pragma unroll
  for (int i = 0; i < 4; ++i){
    const int ci = tid + 128 * i;                 // chunk index = w*64 + lane + 128*i
    const int r = ci >> 3, sc = ci & 7;
    kp[i] = qkv + (size_t)(rowbase + r) * 2304 + 768 + h * 64 + (((sc ^ (r & 7)) & 7) << 3);
  }
  // V staging: thread covers cols dh0,dh0+1 x kv rows vs*16..vs*16+15
  const int dh0 = (tid & 31) * 2, vs = tid >> 5;  // vs in 0..3
  const u16* vp = qkv + (size_t)(rowbase + vs * 16) * 2304 + 1536 + h * 64 + dh0;
  u16x2 vr[16];
  // bias: per (lane, ni); maps onto cvt_biasT's 256-thread tiling: tid' = (2w+ni)*64+16g+l16
  const unsigned char* bTbase = biasT + ((size_t)(h * 32 + qt) * 32) * 4096;
  const unsigned char* bTn[2] = {
    bTbase + (size_t)(((2 * w + 0) << 6) | (g << 4) | l16) * 16,
    bTbase + (size_t)(((2 * w + 1) << 6) | (g << 4) | l16) * 16 };
  u32x4 brW[2], bnW[2];

  // Q fragments: wave owns q rows q0 + w*32 + 16*ni + l16
  s16x8 qf0[2], qf1[2];
#pragma unroll
  for (int ni = 0; ni < 2; ++ni){
    const u16* qrow = qkv + (size_t)(rowbase + q0 + w * 32 + 16 * ni + l16) * 2304 + h * 64;
    qf0[ni] = *(const s16x8*)(qrow + 8 * g);
    qf1[ni] = *(const s16x8*)(qrow + 32 + 8 * g);
  }

  f32x4 oacc[2][4] = {};                          // [ni(q-frag)][ni2(dh-frag)]
  float mrun[2] = {-3.0e38f, -3.0e38f}, lrun[2] = {0.f, 0.f};
  const int sw = l16 & 7;

  // prologue: stage tile 0
  {
#pragma unroll
    for (int i = 0; i < 4; ++i)
      gld16(kp[i], (char*)Ks[0] + w * 1024 + i * 2048);
#pragma unroll
    for (int i = 0; i < 16; ++i) vr[i] = *(const u16x2*)(vp + (size_t)i * 2304);
    brW[0] = *(const u32x4*)(bTn[0]);
    brW[1] = *(const u32x4*)(bTn[1]);
    s16x8 vA0, vA1, vB0, vB1;
#pragma unroll
    for (int j = 0; j < 8; ++j){
      vA0[j] = (short)vr[j][0];     vB0[j] = (short)vr[j][1];
      vA1[j] = (short)vr[8 + j][0]; vB1[j] = (short)vr[8 + j][1];
    }
    *(s16x8*)(Vt[0] + dh0 * 64 + (((2 * vs    ) ^ (dh0 & 7)) << 3)) = vA0;
    *(s16x8*)(Vt[0] + dh0 * 64 + (((2 * vs + 1) ^ (dh0 & 7)) << 3)) = vA1;
    *(s16x8*)(Vt[0] + (dh0 + 1) * 64 + (((2 * vs    ) ^ ((dh0 + 1) & 7)) << 3)) = vB0;
    *(s16x8*)(Vt[0] + (dh0 + 1) * 64 + (((2 * vs + 1) ^ ((dh0 + 1) & 7)) << 3)) = vB1;
  }
  __syncthreads();

  for (int t = 0; t < 32; ++t){
    const int cb = t & 1;
    if (t < 31){  // prefetch tile t+1
      const size_t koff = (size_t)(t + 1) * 64 * 2304;
#pragma unroll
      for (int i = 0; i < 4; ++i)
        gld16(kp[i] + koff, (char*)Ks[cb ^ 1] + w * 1024 + i * 2048);
      const u16* p = vp + koff;
#pragma unroll
      for (int i = 0; i < 16; ++i) vr[i] = *(const u16x2*)(p + (size_t)i * 2304);
      bnW[0] = *(const u32x4*)(bTn[0] + (size_t)(t + 1) * 4096);
      bnW[1] = *(const u32x4*)(bTn[1] + (size_t)(t + 1) * 4096);
    }

    // S2^T = K * Q2^T: kf read once per mi, reused for both q-frags
    f32x4 st[4][2];
    __builtin_amdgcn_s_setprio(1);
#pragma unroll
    for (int mi = 0; mi < 4; ++mi){
      const int row = l16 + 16 * mi;
      s16x8 kf0 = *(const s16x8*)(Ks[cb] + row * 64 + ((g ^ sw) << 3));
      s16x8 kf1 = *(const s16x8*)(Ks[cb] + row * 64 + (((g + 4) ^ sw) << 3));
#pragma unroll
      for (int ni = 0; ni < 2; ++ni){
        f32x4 z = {};
        z = mfma16(kf0, qf0[ni], z);
        st[mi][ni] = mfma16(kf1, qf1[ni], z);
      }
    }
    __builtin_amdgcn_s_setprio(0);

    // + fp8 bias (regs) + online softmax (per q-frag ni; lane owns q = w*32+16ni+l16)
#pragma unroll
    for (int ni = 0; ni < 2; ++ni){
      float mloc[4];
#pragma unroll
      for (int mi = 0; mi < 4; ++mi){
        f32x2 lo = upk_fp8<false>(brW[ni][mi]);
        f32x2 hi = upk_fp8<true>(brW[ni][mi]);
        st[mi][ni][0] = fmaf(lo[0], BINV, st[mi][ni][0]);
        st[mi][ni][1] = fmaf(lo[1], BINV, st[mi][ni][1]);
        st[mi][ni][2] = fmaf(hi[0], BINV, st[mi][ni][2]);
        st[mi][ni][3] = fmaf(hi[1], BINV, st[mi][ni][3]);
        mloc[mi] = fmaxf(fmaxf(st[mi][ni][0], st[mi][ni][1]),
                         fmaxf(st[mi][ni][2], st[mi][ni][3]));
      }
      float tmax = fmaxf(fmaxf(mloc[0], mloc[1]), fmaxf(mloc[2], mloc[3]));
      tmax = fmaxf(tmax, __shfl_xor(tmax, 16));
      tmax = fmaxf(tmax, __shfl_xor(tmax, 32));
      if (!__all(tmax <= mrun[ni] + 8.f)){       // defer-max (T13)
        float mnew = fmaxf(mrun[ni], tmax);
        float al = fexp2(mrun[ni] - mnew);
        mrun[ni] = mnew;
        lrun[ni] *= al;
#pragma unroll
        for (int r = 0; r < 4; ++r){
          float aq = __shfl(al, 4 * g + r);
#pragma unroll
          for (int ni2 = 0; ni2 < 4; ++ni2) oacc[ni][ni2][r] *= aq;
        }
      }
      float ssum = 0.f;
#pragma unroll
      for (int mi = 0; mi < 4; ++mi){
        u16x4 pk;
#pragma unroll
        for (int r = 0; r < 4; ++r){
          float pv = fexp2(st[mi][ni][r] - mrun[ni]);
          ssum += pv;
          pk[r] = f2bf(pv);
        }
        *(u16x4*)(Pl[w] + (16 * ni + l16) * 64 + (((2*mi + (g >> 1)) ^ sw) << 3) + 4 * (g & 1)) = pk;
      }
      ssum += __shfl_xor(ssum, 16);
      ssum += __shfl_xor(ssum, 32);
      lrun[ni] += ssum;
    }

    // O += P @ V: vf read once per (ks2, ni2), reused for both q-frags
    __builtin_amdgcn_s_setprio(1);
#pragma unroll
    for (int ks2 = 0; ks2 < 2; ++ks2){
      s16x8 pf[2];
#pragma unroll
      for (int ni = 0; ni < 2; ++ni)
        pf[ni] = *(const s16x8*)(Pl[w] + (16 * ni + l16) * 64 + (((4*ks2 + g) ^ sw) << 3));
#pragma unroll
      for (int ni2 = 0; ni2 < 4; ++ni2){
        const int dh = l16 + 16 * ni2;
        s16x8 vf = *(const s16x8*)(Vt[cb] + dh * 64 + (((4*ks2 + g) ^ sw) << 3));
#pragma unroll
        for (int ni = 0; ni < 2; ++ni)
          oacc[ni][ni2] = mfma16(pf[ni], vf, oacc[ni][ni2]);
      }
    }
    __builtin_amdgcn_s_setprio(0);

    if (t < 31){  // write V(t+1) into Vt[cb^1]; carry bias regs
      s16x8 vA0, vA1, vB0, vB1;
#pragma unroll
      for (int j = 0; j < 8; ++j){
        vA0[j] = (short)vr[j][0];     vB0[j] = (short)vr[j][1];
        vA1[j] = (short)vr[8 + j][0]; vB1[j] = (short)vr[8 + j][1];
      }
      *(s16x8*)(Vt[cb ^ 1] + dh0 * 64 + (((2 * vs    ) ^ (dh0 & 7)) << 3)) = vA0;
      *(s16x8*)(Vt[cb ^ 1] + dh0 * 64 + (((2 * vs + 1) ^ (dh0 & 7)) << 3)) = vA1;
      *(s16x8*)(Vt[cb ^ 1] + (dh0 + 1) * 64 + (((2 * vs    ) ^ ((dh0 + 1) & 7)) << 3)) = vB0;
      *(s16x8*)(Vt[cb ^ 1] + (dh0 + 1) * 64 + (((2 * vs + 1) ^ ((dh0 + 1) & 7)) << 3)) = vB1;
      brW[0] = bnW[0]; brW[1] = bnW[1];
    }
    __syncthreads();
  }

  // finalize: rows q = q0 + w*32 + 16ni + 4g + r; cols dh = l16 + 16ni2
#pragma unroll
  for (int ni = 0; ni < 2; ++ni){
#pragma unroll
    for (int r = 0; r < 4; ++r){
      float lq = __shfl(lrun[ni], 4 * g + r);
      float inv = 1.0f / lq;
      const int row = rowbase + q0 + w * 32 + 16 * ni + 4 * g + r;
#pragma unroll
      for (int ni2 = 0; ni2 < 4; ++ni2)
        out[(size_t)row * 768 + h * 64 + l16 + 16 * ni2] = f2bf(oacc[ni][ni2][r] * inv);
    }
  }
}

// ============================== host ==============================
extern "C" void kernel_launch(void* const* d_in, const int* in_sizes, int n_in,
                              void* d_out, int out_size, void* d_ws, size_t ws_size,
                              hipStream_t stream){
  const float* in_x    = (const float*)d_in[0];
  const float* in_ctx  = (const float*)d_in[1];
  const float* in_bias = (const float*)d_in[2];
  const float* ln1_w = (const float*)d_in[3];
  const float* ln1_b = (const float*)d_in[4];
  const float* w_qkv = (const float*)d_in[5];
  const float* w_so  = (const float*)d_in[6];
  const float* b_so  = (const float*)d_in[7];
  const float* ln2_w = (const float*)d_in[8];
  const float* ln2_b = (const float*)d_in[9];
  const float* w_q   = (const float*)d_in[10];
  const float* w_k   = (const float*)d_in[11];
  const float* w_v   = (const float*)d_in[12];
  const float* w_co  = (const float*)d_in[13];
  const float* b_co  = (const float*)d_in[14];
  const float* ln3_w = (const float*)d_in[15];
  const float* ln3_b = (const float*)d_in[16];
  const float* w_f1  = (const float*)d_in[17];
  const float* b_f1  = (const float*)d_in[18];
  const float* w_f2  = (const float*)d_in[19];
  const float* b_f2  = (const float*)d_in[20];
  const float* lnout_w = (const float*)d_in[21];
  const float* lnout_b = (const float*)d_in[22];

  char* p = (char*)d_ws;
  u16* xbuf    = (u16*)p;    p += 4096ll * 768 * 2;        // bf16 residual stream
  u16* pbuf    = (u16*)p;    p += 4ll * 4096 * 768 * 2;    // split-K bf16 partials
  u16* xn      = (u16*)p;    p += 4096ll * 768 * 2;
  u16* cn      = (u16*)p;    p += 4ll * 4096 * 768 * 2;    // per-layer LN(context)
  u16* qkvb    = (u16*)p;    p += 4096ll * 2304 * 2;
  u16* attO    = (u16*)p;    p += 4096ll * 768 * 2;
  u16* ffh     = (u16*)p;    p += 4096ll * 3072 * 2;
  u16* wqkvT   = (u16*)p;    p += 4ll * 2304 * 768 * 2;
  u16* wsoT    = (u16*)p;    p += 4ll * 768 * 768 * 2;
  u16* wqT     = (u16*)p;    p += 4ll * 768 * 768 * 2;
  u16* wkvT    = (u16*)p;    p += 4ll * 1536 * 768 * 2;
  u16* wcoT    = (u16*)p;    p += 4ll * 768 * 768 * 2;
  u16* wf1T    = (u16*)p;    p += 4ll * 3072 * 768 * 2;
  u16* wf2T    = (u16*)p;    p += 4ll * 768 * 3072 * 2;
  unsigned char* biasT = (unsigned char*)p; p += 12ll * 2048 * 2048;

  const dim3 tb(32, 8);
  transpose_cvt<<<dim3(72, 24, 4), tb, 0, stream>>>(w_qkv, wqkvT, 768, 2304, 2304ll*768);
  transpose_cvt<<<dim3(96, 24, 4), tb, 0, stream>>>(w_f1,  wf1T,  768, 3072, 3072ll*768);
  transpose_cvt<<<dim3(24, 96, 4), tb, 0, stream>>>(w_f2,  wf2T,  3072, 768, 768ll*3072);
  {
    TPtrs tp;
    for (int i = 0; i < 4; ++i){
      tp.src[i*5+0] = w_so + (size_t)i*768*768;  tp.dst[i*5+0] = wsoT + (size_t)i*768*768;
      tp.src[i*5+1] = w_q  + (size_t)i*768*768;  tp.dst[i*5+1] = wqT  + (size_t)i*768*768;
      tp.src[i*5+2] = w_k  + (size_t)i*768*768;  tp.dst[i*5+2] = wkvT + (size_t)i*1536*768;
      tp.src[i*5+3] = w_v  + (size_t)i*768*768;  tp.dst[i*5+3] = wkvT + (size_t)i*1536*768 + 768ll*768;
      tp.src[i*5+4] = w_co + (size_t)i*768*768;  tp.dst[i*5+4] = wcoT + (size_t)i*768*768;
    }
    transpose_cvt_batch<<<dim3(24, 24, 20), tb, 0, stream>>>(tp);
  }
  cvt_biasT<<<dim3(32, 32, 12), 256, 0, stream>>>(in_bias, biasT);
  ln_pre<<<dim3(1024, 2), 256, 0, stream>>>(in_x, in_ctx, ln1_w, ln1_b, ln2_w, ln2_b,
                                            xn, xbuf, cn);

  const dim3 ag(32, 12, 2);
  for (int i = 0; i < 4; ++i){
    // self-attention block
    gemm_bf16<3><<<dim3(32, 18), 256, 0, stream>>>(xn, 768, wqkvT + (size_t)i*2304*768, 768, 24,
                                                   qkvb, 2304, nullptr, nullptr, nullptr);
    attn_kernel<<<ag, 128, 0, stream>>>(qkvb, biasT, attO);
    gemm_bf16<5><<<dim3(32, 6, 2), 256, 0, stream>>>(attO, 768, wsoT + (size_t)i*768*768, 768, 12,
                                                     pbuf, 768, nullptr, nullptr, nullptr);
    red_ln<u16,2><<<512, 256, 0, stream>>>(pbuf, b_so + i*768, xbuf, xn, ln2_w + i*768, ln2_b + i*768);
    // cross-attention block (merged q/k/v projection)
    gemm_bf16<4><<<dim3(32, 6, 3), 256, 0, stream>>>(xn, 768, wqT + (size_t)i*768*768, 768, 24,
                                                     qkvb, 2304, nullptr,
                                                     cn + (size_t)i*4096*768, wkvT + (size_t)i*1536*768);
    attn_kernel<<<ag, 128, 0, stream>>>(qkvb, biasT, attO);
    gemm_bf16<5><<<dim3(32, 6, 2), 256, 0, stream>>>(attO, 768, wcoT + (size_t)i*768*768, 768, 12,
                                                     pbuf, 768, nullptr, nullptr, nullptr);
    red_ln<u16,2><<<512, 256, 0, stream>>>(pbuf, b_co + i*768, xbuf, xn, ln3_w + i*768, ln3_b + i*768);
    // FFN block
    gemm_bf16<2><<<dim3(32, 24), 256, 0, stream>>>(xn, 768, wf1T + (size_t)i*3072*768, 768, 24,
                                                   ffh, 3072, b_f1 + i*3072, nullptr, nullptr);
    gemm_bf16<5><<<dim3(32, 6, 4), 256, 0, stream>>>(ffh, 3072, wf2T + (size_t)i*768*3072, 3072, 24,
                                                     pbuf, 768, nullptr, nullptr, nullptr);
    if (i < 3)
      red_ln<u16,4><<<512, 256, 0, stream>>>(pbuf, b_f2 + i*768, xbuf, xn, ln1_w + (i+1)*768, ln1_b + (i+1)*768);
    else
      red_ln<float,4><<<512, 256, 0, stream>>>(pbuf, b_f2 + i*768, xbuf, (float*)d_out, lnout_w, lnout_b);
  }
}

// Round 13
// 1266.669 us; speedup vs baseline: 1.0851x; 1.0851x over previous
//
#include <hip/hip_runtime.h>
#include <cstdint>
#include <cstddef>

#define DEV static __device__ __forceinline__

typedef float  f32x4 __attribute__((ext_vector_type(4)));
typedef float  f32x2 __attribute__((ext_vector_type(2)));
typedef short  s16x8 __attribute__((ext_vector_type(8)));
typedef unsigned short u16;
typedef unsigned int   u32;
typedef unsigned int   u32x4 __attribute__((ext_vector_type(4)));
typedef unsigned short u16x2 __attribute__((ext_vector_type(2)));
typedef unsigned short u16x4 __attribute__((ext_vector_type(4)));
typedef __bf16 bf16x8 __attribute__((ext_vector_type(8)));

#define LOG2E 1.4426950408889634f
#define QSCALE_CONST 0.18033688011112042f   /* 0.125 * log2(e) */
#define BSCALE 256.0f                       /* bias fp8 pre-scale */
#define BINV   0.00390625f                  /* 1/256 */

DEV u16 f2bf(float f){ return __builtin_bit_cast(u16, (__bf16)f); }
DEV float bf2f(u16 v){ union { unsigned u; float f; } x; x.u = ((unsigned)v) << 16; return x.f; }

DEV float fexp2(float x){
#if __has_builtin(__builtin_amdgcn_exp2f)
  return __builtin_amdgcn_exp2f(x);
#else
  return exp2f(x);
#endif
}

DEV f32x4 mfma16(s16x8 a, s16x8 b, f32x4 c){
  return __builtin_amdgcn_mfma_f32_16x16x32_bf16(
      __builtin_bit_cast(bf16x8, a), __builtin_bit_cast(bf16x8, b), c, 0, 0, 0);
}

// async global->LDS, 16B per lane
DEV void gld16(const void* g, void* l){
  __builtin_amdgcn_global_load_lds(
      (const __attribute__((address_space(1))) void*)(uintptr_t)g,
      (__attribute__((address_space(3))) void*)(unsigned)(uintptr_t)l,
      16, 0, 0);
}

// ---- fp8 e4m3 (OCP) pack/unpack; HI is compile-time for the builtin ----
#if __has_builtin(__builtin_amdgcn_cvt_pk_fp8_f32) && __has_builtin(__builtin_amdgcn_cvt_pk_f32_fp8)
DEV u32 pk4_fp8(f32x4 v){
  int r = __builtin_amdgcn_cvt_pk_fp8_f32(v[0], v[1], 0, false);
  r     = __builtin_amdgcn_cvt_pk_fp8_f32(v[2], v[3], r, true);
  return (u32)r;
}
template<bool HI>
DEV f32x2 upk_fp8(u32 w){
  return __builtin_amdgcn_cvt_pk_f32_fp8((int)w, HI);
}
#else
DEV unsigned enc1(float x){
  union{float f; unsigned u;} c; c.f = x;
  unsigned s = (c.u >> 24) & 0x80;
  int e = (int)((c.u >> 23) & 0xff) - 127;
  unsigned m = c.u & 0x7fffff;
  if (e >= -6){
    unsigned mant = m >> 20, rem = m & 0xfffff;
    if (rem > 0x80000 || (rem == 0x80000 && (mant & 1))) mant++;
    unsigned eb = (unsigned)(e + 7);
    if (mant == 8){ mant = 0; eb++; }
    if (eb >= 16){ eb = 15; mant = 6; }
    return s | (eb << 3) | mant;
  }
  if (e < -10) return s;
  int sh = -6 - e;
  unsigned full = (1u << 23) | m;
  unsigned mant = full >> (20 + sh);
  unsigned rem  = full & ((1u << (20 + sh)) - 1);
  unsigned half = 1u << (19 + sh);
  if (rem > half || (rem == half && (mant & 1))) mant++;
  if (mant == 8) return s | (1u << 3);
  return s | mant;
}
DEV u32 pk4_fp8(f32x4 v){
  return enc1(v[0]) | (enc1(v[1]) << 8) | (enc1(v[2]) << 16) | (enc1(v[3]) << 24);
}
DEV float dec1(unsigned b){
  int s = (b >> 7) & 1, e = (b >> 3) & 15; float m = (float)(b & 7) * 0.125f;
  float v = e ? ldexpf(1.0f + m, e - 7) : ldexpf(m, -6);
  return s ? -v : v;
}
template<bool HI>
DEV f32x2 upk_fp8(u32 w){
  unsigned lo = HI ? ((w >> 16) & 0xff) : (w & 0xff);
  unsigned h2 = HI ? ((w >> 24) & 0xff) : ((w >> 8) & 0xff);
  f32x2 r; r[0] = dec1(lo); r[1] = dec1(h2); return r;
}
#endif

// ---------------- transpose + fp32->bf16 convert: src[K][N] -> dst[N][K] ----------------
__global__ void __launch_bounds__(256)
transpose_cvt(const float* __restrict__ src, u16* __restrict__ dst, int K, int N,
              size_t dzstride){
  int z = blockIdx.z;
  src += (size_t)z * K * N;
  dst += (size_t)z * dzstride;
  __shared__ float t[32][33];
  int n0 = blockIdx.x * 32, k0 = blockIdx.y * 32;
#pragma unroll
  for (int i = 0; i < 4; ++i)
    t[threadIdx.y + 8*i][threadIdx.x] = src[(size_t)(k0 + threadIdx.y + 8*i) * N + n0 + threadIdx.x];
  __syncthreads();
#pragma unroll
  for (int i = 0; i < 4; ++i)
    dst[(size_t)(n0 + threadIdx.y + 8*i) * K + k0 + threadIdx.x] = f2bf(t[threadIdx.x][threadIdx.y + 8*i]);
}

// ---------------- batched 768x768 transpose (20 weights in one dispatch) ----------------
struct TPtrs { const float* src[20]; u16* dst[20]; };
__global__ void __launch_bounds__(256)
transpose_cvt_batch(TPtrs tp){
  const float* src = tp.src[blockIdx.z];
  u16* dst = tp.dst[blockIdx.z];
  __shared__ float t[32][33];
  int n0 = blockIdx.x * 32, k0 = blockIdx.y * 32;
#pragma unroll
  for (int i = 0; i < 4; ++i)
    t[threadIdx.y + 8*i][threadIdx.x] = src[(size_t)(k0 + threadIdx.y + 8*i) * 768 + n0 + threadIdx.x];
  __syncthreads();
#pragma unroll
  for (int i = 0; i < 4; ++i)
    dst[(size_t)(n0 + threadIdx.y + 8*i) * 768 + k0 + threadIdx.x] = f2bf(t[threadIdx.x][threadIdx.y + 8*i]);
}

// ---------------- bias -> tiled fp8 (log2e*256-scaled) ----------------
__global__ void __launch_bounds__(256)
cvt_biasT(const float* __restrict__ in, unsigned char* __restrict__ out){
  const int kvt = blockIdx.x, qt = blockIdx.y, h = blockIdx.z, tid = threadIdx.x;
  const int q  = qt * 64 + ((tid >> 6) << 4) + (tid & 15);
  const int c0 = kvt * 64 + ((tid >> 4) & 3) * 4;
  const float* src = in + ((size_t)h * 2048 + q) * 2048;
  u32x4 wv;
#pragma unroll
  for (int mi = 0; mi < 4; ++mi){
    f32x4 v = *(const f32x4*)(src + c0 + mi * 16);
#pragma unroll
    for (int r = 0; r < 4; ++r) v[r] = fminf(fmaxf(v[r] * (LOG2E * BSCALE), -448.f), 448.f);
    wv[mi] = pk4_fp8(v);
  }
  *(u32x4*)(out + ((size_t)(h * 32 + qt) * 32 + kvt) * 4096 + tid * 16) = wv;
}

// ---------------- pre-pass LN: stats computed ONCE per row ----------------
__global__ void __launch_bounds__(256)
ln_pre(const float* __restrict__ x, const float* __restrict__ ctx,
       const float* __restrict__ w1, const float* __restrict__ b1,
       const float* __restrict__ w2, const float* __restrict__ b2,
       u16* __restrict__ xn, u16* __restrict__ xbuf, u16* __restrict__ cn){
  const int wv = threadIdx.x >> 6, lane = threadIdx.x & 63;
  const int row = blockIdx.x * 4 + wv;
  const float* xr = (blockIdx.y == 0 ? x : ctx) + (size_t)row * 768;
  f32x4 t[3]; float s = 0.f, s2 = 0.f;
#pragma unroll
  for (int c = 0; c < 3; ++c){
    t[c] = *(const f32x4*)(xr + c * 256 + lane * 4);
#pragma unroll
    for (int j = 0; j < 4; ++j){ s += t[c][j]; s2 += t[c][j] * t[c][j]; }
  }
#pragma unroll
  for (int off = 1; off < 64; off <<= 1){ s += __shfl_xor(s, off); s2 += __shfl_xor(s2, off); }
  float m = s * (1.f/768.f);
  float rstd = rsqrtf(s2 * (1.f/768.f) - m * m + 1e-5f);
  if (blockIdx.y == 0){
#pragma unroll
    for (int c = 0; c < 3; ++c){
      const int col = c * 256 + lane * 4;
      f32x4 wv4 = *(const f32x4*)(w1 + col);
      f32x4 bv4 = *(const f32x4*)(b1 + col);
      u16x4 o, xb;
#pragma unroll
      for (int j = 0; j < 4; ++j){
        o[j]  = f2bf((t[c][j] - m) * rstd * wv4[j] + bv4[j]);
        xb[j] = f2bf(t[c][j]);
      }
      *(u16x4*)(xn   + (size_t)row * 768 + col) = o;
      *(u16x4*)(xbuf + (size_t)row * 768 + col) = xb;
    }
  } else {
#pragma unroll
    for (int i = 0; i < 4; ++i){
      u16* dst = cn + (size_t)i * 4096 * 768 + (size_t)row * 768;
#pragma unroll
      for (int c = 0; c < 3; ++c){
        const int col = c * 256 + lane * 4;
        f32x4 wv4 = *(const f32x4*)(w2 + i * 768 + col);
        f32x4 bv4 = *(const f32x4*)(b2 + i * 768 + col);
        u16x4 o;
#pragma unroll
        for (int j = 0; j < 4; ++j) o[j] = f2bf((t[c][j] - m) * rstd * wv4[j] + bv4[j]);
        *(u16x4*)(dst + col) = o;
      }
    }
  }
}

// ---------------- fused splitK(NZ)-reduce + bias + bf16 residual + LN, 2 rows/wave -----
template<typename OUT, int NZ>
__global__ void __launch_bounds__(256)
red_ln(const u16* __restrict__ pb, const float* __restrict__ biasrow,
       u16* __restrict__ xbuf, OUT* __restrict__ out,
       const float* __restrict__ lw, const float* __restrict__ lb){
  const int wv = threadIdx.x >> 6, lane = threadIdx.x & 63;
  const int row0 = blockIdx.x * 8 + wv * 2;
  const size_t S = 4096ll * 768;
  f32x4 t[2][3]; float s[2] = {0.f, 0.f}, s2[2] = {0.f, 0.f};
#pragma unroll
  for (int rr = 0; rr < 2; ++rr){
    const int row = row0 + rr;
    const u16* p0 = pb + (size_t)row * 768;
    u16* xr = xbuf + (size_t)row * 768;
#pragma unroll
    for (int c = 0; c < 3; ++c){
      const int col = c * 256 + lane * 4;
      f32x4 v = *(const f32x4*)(biasrow + col);
      u16x4 xv = *(const u16x4*)(xr + col);
#pragma unroll
      for (int j = 0; j < 4; ++j) v[j] += bf2f(xv[j]);
#pragma unroll
      for (int z = 0; z < NZ; ++z){
        u16x4 pv = *(const u16x4*)(p0 + z * S + col);
#pragma unroll
        for (int j = 0; j < 4; ++j) v[j] += bf2f(pv[j]);
      }
      u16x4 xo;
#pragma unroll
      for (int j = 0; j < 4; ++j) xo[j] = f2bf(v[j]);
      *(u16x4*)(xr + col) = xo;
      t[rr][c] = v;
#pragma unroll
      for (int j = 0; j < 4; ++j){ s[rr] += v[j]; s2[rr] += v[j] * v[j]; }
    }
  }
#pragma unroll
  for (int off = 1; off < 64; off <<= 1){
#pragma unroll
    for (int rr = 0; rr < 2; ++rr){
      s[rr]  += __shfl_xor(s[rr], off);
      s2[rr] += __shfl_xor(s2[rr], off);
    }
  }
#pragma unroll
  for (int rr = 0; rr < 2; ++rr){
    const int row = row0 + rr;
    float m = s[rr] * (1.f/768.f);
    float rstd = rsqrtf(s2[rr] * (1.f/768.f) - m * m + 1e-5f);
#pragma unroll
    for (int c = 0; c < 3; ++c){
      const int col = c * 256 + lane * 4;
      f32x4 wv4 = *(const f32x4*)(lw + col);
      f32x4 bv4 = *(const f32x4*)(lb + col);
      if constexpr (sizeof(OUT) == 2){
        u16x4 o;
#pragma unroll
        for (int j = 0; j < 4; ++j) o[j] = f2bf((t[rr][c][j] - m) * rstd * wv4[j] + bv4[j]);
        *(u16x4*)((u16*)out + (size_t)row * 768 + col) = o;
      } else {
        f32x4 o;
#pragma unroll
        for (int j = 0; j < 4; ++j) o[j] = (t[rr][c][j] - m) * rstd * wv4[j] + bv4[j];
        *(f32x4*)((float*)out + (size_t)row * 768 + col) = o;
      }
    }
  }
}

// ---------------- bf16 GEMM, 128x128, double-buffered, XCD-swizzled ----------------
// __launch_bounds__(256,3): cap VGPR so >=3 blocks/CU co-resident (m97-class occupancy).
template<int EPI>
__global__ void __launch_bounds__(256, 3)
gemm_bf16(const u16* __restrict__ A, int lda, const u16* __restrict__ Bt, int ldb,
          int nk, u16* __restrict__ Cb, int ldc,
          const float* __restrict__ bias,
          const u16* __restrict__ A2, const u16* __restrict__ Bt2){
  __shared__ u16 As[2][128 * 32];
  __shared__ u16 Bs[2][128 * 32];
  float colscale = 1.0f;
  if constexpr (EPI == 4){
    const int z = blockIdx.z;
    if (z == 0){ colscale = QSCALE_CONST; }
    else { A = A2; Bt = Bt2 + (size_t)(z - 1) * 768 * 768; }
    Cb += z * 768;
  }
  if constexpr (EPI == 5){
    const int z = blockIdx.z;
    A  += (size_t)z * nk * 32;
    Bt += (size_t)z * nk * 32;
    Cb += (size_t)z * 4096 * 768;
  }
  // bijective XCD-chunked swizzle (m204) on the 2D slice
  const int gx = gridDim.x, nwg = gx * gridDim.y;
  int lin = blockIdx.y * gx + blockIdx.x;
  {
    const int qq = nwg >> 3, rr = nwg & 7;
    const int xc = lin & 7, oo = lin >> 3;
    lin = (xc < rr ? xc * (qq + 1) : rr * (qq + 1) + (xc - rr) * qq) + oo;
  }
  const int m0 = (lin % gx) * 128, n0 = (lin / gx) * 128;

  const int tid = threadIdx.x, w = tid >> 6, lane = tid & 63;
  const int l16 = lane & 15, g = lane >> 4;
  const int wm = (w >> 1) * 64, wn = (w & 1) * 64;
  f32x4 acc[4][4] = {};

  const u16* a0 = A  + (size_t)(m0 + (tid >> 2)) * lda + (tid & 3) * 8;
  const u16* a1 = A  + (size_t)(m0 + (tid >> 2) + 64) * lda + (tid & 3) * 8;
  const u16* b0 = Bt + (size_t)(n0 + (tid >> 2)) * ldb + (tid & 3) * 8;
  const u16* b1 = Bt + (size_t)(n0 + (tid >> 2) + 64) * ldb + (tid & 3) * 8;

  {
    char* ab = (char*)As[0]; char* bb = (char*)Bs[0];
    gld16(a0, ab + w * 1024); gld16(a1, ab + 4096 + w * 1024);
    gld16(b0, bb + w * 1024); gld16(b1, bb + 4096 + w * 1024);
  }
  __syncthreads();

  int cb = 0;
  for (int kt = 0; kt < nk; ++kt){
    if (kt + 1 < nk){
      const int k1 = (kt + 1) * 32;
      char* ab = (char*)As[cb ^ 1]; char* bb = (char*)Bs[cb ^ 1];
      gld16(a0 + k1, ab + w * 1024); gld16(a1 + k1, ab + 4096 + w * 1024);
      gld16(b0 + k1, bb + w * 1024); gld16(b1 + k1, bb + 4096 + w * 1024);
    }
    const u16* Ab = As[cb]; const u16* Bb = Bs[cb];
    s16x8 af[4], bfv[4];
#pragma unroll
    for (int mi = 0; mi < 4; ++mi)
      af[mi] = *(const s16x8*)(Ab + (wm + mi*16 + l16) * 32 + 8 * g);
#pragma unroll
    for (int ni = 0; ni < 4; ++ni)
      bfv[ni] = *(const s16x8*)(Bb + (wn + ni*16 + l16) * 32 + 8 * g);
#pragma unroll
    for (int mi = 0; mi < 4; ++mi)
#pragma unroll
      for (int ni = 0; ni < 4; ++ni)
        acc[mi][ni] = mfma16(af[mi], bfv[ni], acc[mi][ni]);
    __syncthreads();
    cb ^= 1;
  }

  // epilogue: C/D layout col = lane&15, row = 4*(lane>>4)+r
#pragma unroll
  for (int mi = 0; mi < 4; ++mi){
    const int rg = m0 + wm + mi*16 + 4*g;
#pragma unroll
    for (int ni = 0; ni < 4; ++ni){
      const int col = n0 + wn + ni*16 + l16;
      f32x4 v = acc[mi][ni];
#pragma unroll
      for (int r = 0; r < 4; ++r){
        const int row = rg + r;
        if constexpr (EPI == 2){
          float t = v[r] + bias[col];
          float ge = 0.5f * t * (1.0f + erff(t * 0.7071067811865476f));
          Cb[(size_t)row * ldc + col] = f2bf(ge);
        } else if constexpr (EPI == 3){
          float sc = (col < 768) ? QSCALE_CONST : 1.0f;
          Cb[(size_t)row * ldc + col] = f2bf(v[r] * sc);
        } else if constexpr (EPI == 4){
          Cb[(size_t)row * ldc + col] = f2bf(v[r] * colscale);
        } else {
          Cb[(size_t)row * 768 + col] = f2bf(v[r]);
        }
      }
    }
  }
}

// ---------------- fused flash attention v5.1 (round-11 proven): 4 waves x 16 q ---------
__global__ void __launch_bounds__(256)
attn_kernel(const u16* __restrict__ qkv, const unsigned char* __restrict__ biasT,
            u16* __restrict__ out){
  __shared__ __align__(16) u16 Ks[2][4096];
  __shared__ __align__(16) u16 Vt[2][4096];
  __shared__ __align__(16) u16 Pl[4][1024];

  const int tid = threadIdx.x, w = tid >> 6, lane = tid & 63;
  const int l16 = lane & 15, g = lane >> 4;
  const int qt = blockIdx.x, h = blockIdx.y, b = blockIdx.z;
  const int rowbase = b * 2048, q0 = qt * 64;

  const int ci0 = w * 64 + lane, ci1 = ci0 + 256;
  const int r0 = ci0 >> 3, sc0 = ci0 & 7, r1 = ci1 >> 3, sc1 = ci1 & 7;
  const u16* kp0 = qkv + (size_t)(rowbase + r0) * 2304 + 768 + h * 64 + (((sc0 ^ (r0 & 7)) & 7) << 3);
  const u16* kp1 = qkv + (size_t)(rowbase + r1) * 2304 + 768 + h * 64 + (((sc1 ^ (r1 & 7)) & 7) << 3);
  const int dh0 = (tid & 31) * 2, vs = tid >> 5;
  const u16* vp = qkv + (size_t)(rowbase + vs * 8) * 2304 + 1536 + h * 64 + dh0;
  u16x2 vr[8];
  const unsigned char* bT = biasT + ((size_t)(h * 32 + qt) * 32) * 4096 + tid * 16;
  u32x4 brW, bnW;

  const u16* qrow = qkv + (size_t)(rowbase + q0 + w * 16 + l16) * 2304 + h * 64;
  s16x8 qf0 = *(const s16x8*)(qrow + 8 * g);
  s16x8 qf1 = *(const s16x8*)(qrow + 32 + 8 * g);

  f32x4 oacc[4] = {};
  float mrun = -3.0e38f, lrun = 0.f;
  const int sw = l16 & 7;

  {
    char* kb = (char*)Ks[0] + w * 1024;
    gld16(kp0, kb); gld16(kp1, kb + 4096);
#pragma unroll
    for (int i = 0; i < 8; ++i) vr[i] = *(const u16x2*)(vp + (size_t)i * 2304);
    brW = *(const u32x4*)(bT);
    s16x8 vA, vB;
#pragma unroll
    for (int j = 0; j < 8; ++j){ vA[j] = (short)vr[j][0]; vB[j] = (short)vr[j][1]; }
    *(s16x8*)(Vt[0] + dh0 * 64 + ((vs ^ (dh0 & 7)) << 3)) = vA;
    *(s16x8*)(Vt[0] + (dh0 + 1) * 64 + ((vs ^ ((dh0 + 1) & 7)) << 3)) = vB;
  }
  __syncthreads();

  for (int t = 0; t < 32; ++t){
    const int cb = t & 1;
    if (t < 31){
      const size_t koff = (size_t)(t + 1) * 64 * 2304;
      char* kb = (char*)Ks[cb ^ 1] + w * 1024;
      gld16(kp0 + koff, kb); gld16(kp1 + koff, kb + 4096);
      const u16* p = vp + koff;
#pragma unroll
      for (int i = 0; i < 8; ++i) vr[i] = *(const u16x2*)(p + (size_t)i * 2304);
      bnW = *(const u32x4*)(bT + (size_t)(t + 1) * 4096);
    }

    f32x4 st[4];
    __builtin_amdgcn_s_setprio(1);
#pragma unroll
    for (int mi = 0; mi < 4; ++mi){
      const int row = l16 + 16 * mi;
      s16x8 kf0 = *(const s16x8*)(Ks[cb] + row * 64 + ((g ^ sw) << 3));
      s16x8 kf1 = *(const s16x8*)(Ks[cb] + row * 64 + (((g + 4) ^ sw) << 3));
      f32x4 z = {};
      z = mfma16(kf0, qf0, z);
      st[mi] = mfma16(kf1, qf1, z);
    }
    __builtin_amdgcn_s_setprio(0);

    float mloc[4];
#pragma unroll
    for (int mi = 0; mi < 4; ++mi){
      f32x2 lo = upk_fp8<false>(brW[mi]);
      f32x2 hi = upk_fp8<true>(brW[mi]);
      st[mi][0] = fmaf(lo[0], BINV, st[mi][0]);
      st[mi][1] = fmaf(lo[1], BINV, st[mi][1]);
      st[mi][2] = fmaf(hi[0], BINV, st[mi][2]);
      st[mi][3] = fmaf(hi[1], BINV, st[mi][3]);
      mloc[mi] = fmaxf(fmaxf(st[mi][0], st[mi][1]), fmaxf(st[mi][2], st[mi][3]));
    }
    float tmax = fmaxf(fmaxf(mloc[0], mloc[1]), fmaxf(mloc[2], mloc[3]));
    tmax = fmaxf(tmax, __shfl_xor(tmax, 16));
    tmax = fmaxf(tmax, __shfl_xor(tmax, 32));
    if (!__all(tmax <= mrun + 8.f)){
      float mnew = fmaxf(mrun, tmax);
      float al = fexp2(mrun - mnew);
      mrun = mnew;
      lrun *= al;
#pragma unroll
      for (int r = 0; r < 4; ++r){
        float aq = __shfl(al, 4 * g + r);
#pragma unroll
        for (int ni = 0; ni < 4; ++ni) oacc[ni][r] *= aq;
      }
    }
    float ssum = 0.f;
#pragma unroll
    for (int mi = 0; mi < 4; ++mi){
      u16x4 pk;
#pragma unroll
      for (int r = 0; r < 4; ++r){
        float pv = fexp2(st[mi][r] - mrun);
        ssum += pv;
        pk[r] = f2bf(pv);
      }
      *(u16x4*)(Pl[w] + l16 * 64 + (((2*mi + (g >> 1)) ^ sw) << 3) + 4 * (g & 1)) = pk;
    }
    ssum += __shfl_xor(ssum, 16);
    ssum += __shfl_xor(ssum, 32);
    lrun += ssum;

    __builtin_amdgcn_s_setprio(1);
#pragma unroll
    for (int ks2 = 0; ks2 < 2; ++ks2){
      s16x8 pf = *(const s16x8*)(Pl[w] + l16 * 64 + (((4*ks2 + g) ^ sw) << 3));
#pragma unroll
      for (int ni = 0; ni < 4; ++ni){
        const int dh = l16 + 16 * ni;
        s16x8 vf = *(const s16x8*)(Vt[cb] + dh * 64 + (((4*ks2 + g) ^ sw) << 3));
        oacc[ni] = mfma16(pf, vf, oacc[ni]);
      }
    }
    __builtin_amdgcn_s_setprio(0);

    if (t < 31){
      s16x8 vA, vB;
#pragma unroll
      for (int j = 0; j < 8; ++j){ vA[j] = (short)vr[j][0]; vB[j] = (short)vr[j][1]; }
      *(s16x8*)(Vt[cb ^ 1] + dh0 * 64 + ((vs ^ (dh0 & 7)) << 3)) = vA;
      *(s16x8*)(Vt[cb ^ 1] + (dh0 + 1) * 64 + ((vs ^ ((dh0 + 1) & 7)) << 3)) = vB;
      brW = bnW;
    }
    __syncthreads();
  }

#pragma unroll
  for (int r = 0; r < 4; ++r){
    float lq = __shfl(lrun, 4 * g + r);
    float inv = 1.0f / lq;
    const int row = rowbase + q0 + w * 16 + 4 * g + r;
#pragma unroll
    for (int ni = 0; ni < 4; ++ni)
      out[(size_t)row * 768 + h * 64 + l16 + 16 * ni] = f2bf(oacc[ni][r] * inv);
  }
}

// ============================== host ==============================
extern "C" void kernel_launch(void* const* d_in, const int* in_sizes, int n_in,
                              void* d_out, int out_size, void* d_ws, size_t ws_size,
                              hipStream_t stream){
  const float* in_x    = (const float*)d_in[0];
  const float* in_ctx  = (const float*)d_in[1];
  const float* in_bias = (const float*)d_in[2];
  const float* ln1_w = (const float*)d_in[3];
  const float* ln1_b = (const float*)d_in[4];
  const float* w_qkv = (const float*)d_in[5];
  const float* w_so  = (const float*)d_in[6];
  const float* b_so  = (const float*)d_in[7];
  const float* ln2_w = (const float*)d_in[8];
  const float* ln2_b = (const float*)d_in[9];
  const float* w_q   = (const float*)d_in[10];
  const float* w_k   = (const float*)d_in[11];
  const float* w_v   = (const float*)d_in[12];
  const float* w_co  = (const float*)d_in[13];
  const float* b_co  = (const float*)d_in[14];
  const float* ln3_w = (const float*)d_in[15];
  const float* ln3_b = (const float*)d_in[16];
  const float* w_f1  = (const float*)d_in[17];
  const float* b_f1  = (const float*)d_in[18];
  const float* w_f2  = (const float*)d_in[19];
  const float* b_f2  = (const float*)d_in[20];
  const float* lnout_w = (const float*)d_in[21];
  const float* lnout_b = (const float*)d_in[22];

  char* p = (char*)d_ws;
  u16* xbuf    = (u16*)p;    p += 4096ll * 768 * 2;        // bf16 residual stream
  u16* pbuf    = (u16*)p;    p += 4ll * 4096 * 768 * 2;    // split-K bf16 partials
  u16* xn      = (u16*)p;    p += 4096ll * 768 * 2;
  u16* cn      = (u16*)p;    p += 4ll * 4096 * 768 * 2;    // per-layer LN(context)
  u16* qkvb    = (u16*)p;    p += 4096ll * 2304 * 2;
  u16* attO    = (u16*)p;    p += 4096ll * 768 * 2;
  u16* ffh     = (u16*)p;    p += 4096ll * 3072 * 2;
  u16* wqkvT   = (u16*)p;    p += 4ll * 2304 * 768 * 2;
  u16* wsoT    = (u16*)p;    p += 4ll * 768 * 768 * 2;
  u16* wqT     = (u16*)p;    p += 4ll * 768 * 768 * 2;
  u16* wkvT    = (u16*)p;    p += 4ll * 1536 * 768 * 2;
  u16* wcoT    = (u16*)p;    p += 4ll * 768 * 768 * 2;
  u16* wf1T    = (u16*)p;    p += 4ll * 3072 * 768 * 2;
  u16* wf2T    = (u16*)p;    p += 4ll * 768 * 3072 * 2;
  unsigned char* biasT = (unsigned char*)p; p += 12ll * 2048 * 2048;

  const dim3 tb(32, 8);
  transpose_cvt<<<dim3(72, 24, 4), tb, 0, stream>>>(w_qkv, wqkvT, 768, 2304, 2304ll*768);
  transpose_cvt<<<dim3(96, 24, 4), tb, 0, stream>>>(w_f1,  wf1T,  768, 3072, 3072ll*768);
  transpose_cvt<<<dim3(24, 96, 4), tb, 0, stream>>>(w_f2,  wf2T,  3072, 768, 768ll*3072);
  {
    TPtrs tp;
    for (int i = 0; i < 4; ++i){
      tp.src[i*5+0] = w_so + (size_t)i*768*768;  tp.dst[i*5+0] = wsoT + (size_t)i*768*768;
      tp.src[i*5+1] = w_q  + (size_t)i*768*768;  tp.dst[i*5+1] = wqT  + (size_t)i*768*768;
      tp.src[i*5+2] = w_k  + (size_t)i*768*768;  tp.dst[i*5+2] = wkvT + (size_t)i*1536*768;
      tp.src[i*5+3] = w_v  + (size_t)i*768*768;  tp.dst[i*5+3] = wkvT + (size_t)i*1536*768 + 768ll*768;
      tp.src[i*5+4] = w_co + (size_t)i*768*768;  tp.dst[i*5+4] = wcoT + (size_t)i*768*768;
    }
    transpose_cvt_batch<<<dim3(24, 24, 20), tb, 0, stream>>>(tp);
  }
  cvt_biasT<<<dim3(32, 32, 12), 256, 0, stream>>>(in_bias, biasT);
  ln_pre<<<dim3(1024, 2), 256, 0, stream>>>(in_x, in_ctx, ln1_w, ln1_b, ln2_w, ln2_b,
                                            xn, xbuf, cn);

  const dim3 ag(32, 12, 2);
  for (int i = 0; i < 4; ++i){
    // self-attention block
    gemm_bf16<3><<<dim3(32, 18), 256, 0, stream>>>(xn, 768, wqkvT + (size_t)i*2304*768, 768, 24,
                                                   qkvb, 2304, nullptr, nullptr, nullptr);
    attn_kernel<<<ag, 256, 0, stream>>>(qkvb, biasT, attO);
    gemm_bf16<5><<<dim3(32, 6, 2), 256, 0, stream>>>(attO, 768, wsoT + (size_t)i*768*768, 768, 12,
                                                     pbuf, 768, nullptr, nullptr, nullptr);
    red_ln<u16,2><<<512, 256, 0, stream>>>(pbuf, b_so + i*768, xbuf, xn, ln2_w + i*768, ln2_b + i*768);
    // cross-attention block (merged q/k/v projection)
    gemm_bf16<4><<<dim3(32, 6, 3), 256, 0, stream>>>(xn, 768, wqT + (size_t)i*768*768, 768, 24,
                                                     qkvb, 2304, nullptr,
                                                     cn + (size_t)i*4096*768, wkvT + (size_t)i*1536*768);
    attn_kernel<<<ag, 256, 0, stream>>>(qkvb, biasT, attO);
    gemm_bf16<5><<<dim3(32, 6, 2), 256, 0, stream>>>(attO, 768, wcoT + (size_t)i*768*768, 768, 12,
                                                     pbuf, 768, nullptr, nullptr, nullptr);
    red_ln<u16,2><<<512, 256, 0, stream>>>(pbuf, b_co + i*768, xbuf, xn, ln3_w + i*768, ln3_b + i*768);
    // FFN block
    gemm_bf16<2><<<dim3(32, 24), 256, 0, stream>>>(xn, 768, wf1T + (size_t)i*3072*768, 768, 24,
                                                   ffh, 3072, b_f1 + i*3072, nullptr, nullptr);
    gemm_bf16<5><<<dim3(32, 6, 4), 256, 0, stream>>>(ffh, 3072, wf2T + (size_t)i*768*3072, 3072, 24,
                                                     pbuf, 768, nullptr, nullptr, nullptr);
    if (i < 3)
      red_ln<u16,4><<<512, 256, 0, stream>>>(pbuf, b_f2 + i*768, xbuf, xn, ln1_w + (i+1)*768, ln1_b + (i+1)*768);
    else
      red_ln<float,4><<<512, 256, 0, stream>>>(pbuf, b_f2 + i*768, xbuf, (float*)d_out, lnout_w, lnout_b);
  }
}